// Round 6
// baseline (471.802 us; speedup 1.0000x reference)
//
#include <hip/hip_runtime.h>
#include <hip/hip_bf16.h>

typedef unsigned short u16;
typedef unsigned int u32;
typedef __attribute__((ext_vector_type(8))) short short8;
typedef __attribute__((ext_vector_type(4))) float floatx4;

__device__ __forceinline__ float b2f(u16 u) {
    u32 x = ((u32)u) << 16;
    return __builtin_bit_cast(float, x);
}
// scalar f32 -> bf16 (RNE), branch-free
__device__ __forceinline__ u16 f2b(float f) {
    u32 x = __builtin_bit_cast(u32, f);
    return (u16)((x + 0x7fffu + ((x >> 16) & 1u)) >> 16);
}
// packed f32x2 -> bf16x2: single v_cvt_pk_bf16_f32 on gfx950
__device__ __forceinline__ u32 pack2(float lo, float hi) {
#if __has_builtin(__builtin_amdgcn_cvt_pk_bf16_f32)
    auto h = __builtin_amdgcn_cvt_pk_bf16_f32(lo, hi);
    return __builtin_bit_cast(u32, h);
#else
    u32 xl = __builtin_bit_cast(u32, lo);
    u32 xh = __builtin_bit_cast(u32, hi);
    u32 rl = (xl + 0x7fffu + ((xl >> 16) & 1u)) >> 16;
    u32 rh = (xh + 0x7fffu + ((xh >> 16) & 1u)) & 0xffff0000u;
    return rh | rl;
#endif
}

// ---------------------------------------------------------------------------
// GEMM: C[m,n] = scale * sum_k A[m,k] * B[n,k]  (+ bias[n])
// A: (M,K) row-major, f32 (AF32=true) or bf16 (false)
// B: (N,K) row-major f32 (weights straight from d_in)
// C: bf16 (Cb) or f32 (Cf). f32 acc via MFMA. 128x128 tile, BK=64.
// ---------------------------------------------------------------------------
template<bool AF32>
__global__ __launch_bounds__(256) void gemm_bt_bias(
    const void* __restrict__ Ap, const float* __restrict__ B,
    u16* __restrict__ Cb, float* __restrict__ Cf, const float* __restrict__ bias,
    int M, int N, int K, float scale)
{
    __shared__ __align__(16) u16 a_lds[128][72];
    __shared__ __align__(16) u16 b_lds[128][72];
    const int tid = threadIdx.x;
    const int lane = tid & 63, wv = tid >> 6;
    const int quad = lane >> 4, l15 = lane & 15;
    const int tm = blockIdx.x, tn = blockIdx.y;
    const int wm = (wv >> 1) * 64, wn = (wv & 1) * 64;
    (void)M;

    floatx4 acc[4][4];
#pragma unroll
    for (int i = 0; i < 4; ++i)
#pragma unroll
        for (int j = 0; j < 4; ++j) acc[i][j] = (floatx4)0.f;

    for (int k0 = 0; k0 < K; k0 += 64) {
#pragma unroll
        for (int r = 0; r < 4; ++r) {
            int idx = r * 256 + tid;
            int row = idx >> 3, ch = (idx & 7) * 8;
            if constexpr (AF32) {
                const float* A = (const float*)Ap;
                const float* src = A + (size_t)(tm * 128 + row) * K + k0 + ch;
                float4 f0 = *(const float4*)src;
                float4 f1 = *(const float4*)(src + 4);
                uint4 pk;
                pk.x = pack2(f0.x, f0.y);
                pk.y = pack2(f0.z, f0.w);
                pk.z = pack2(f1.x, f1.y);
                pk.w = pack2(f1.z, f1.w);
                *(uint4*)&a_lds[row][ch] = pk;
            } else {
                const u16* A = (const u16*)Ap;
                *(uint4*)&a_lds[row][ch] =
                    *(const uint4*)(A + (size_t)(tm * 128 + row) * K + k0 + ch);
            }
            {
                const float* src = B + (size_t)(tn * 128 + row) * K + k0 + ch;
                float4 f0 = *(const float4*)src;
                float4 f1 = *(const float4*)(src + 4);
                uint4 pk;
                pk.x = pack2(f0.x, f0.y);
                pk.y = pack2(f0.z, f0.w);
                pk.z = pack2(f1.x, f1.y);
                pk.w = pack2(f1.z, f1.w);
                *(uint4*)&b_lds[row][ch] = pk;
            }
        }
        __syncthreads();
#pragma unroll
        for (int dc = 0; dc < 2; ++dc) {
            short8 af[4], bf[4];
#pragma unroll
            for (int mi = 0; mi < 4; ++mi)
                af[mi] = *(const short8*)&a_lds[wm + mi * 16 + l15][dc * 32 + quad * 8];
#pragma unroll
            for (int ni = 0; ni < 4; ++ni)
                bf[ni] = *(const short8*)&b_lds[wn + ni * 16 + l15][dc * 32 + quad * 8];
#pragma unroll
            for (int mi = 0; mi < 4; ++mi)
#pragma unroll
                for (int ni = 0; ni < 4; ++ni)
                    acc[mi][ni] = __builtin_amdgcn_mfma_f32_16x16x32_bf16(
                        af[mi], bf[ni], acc[mi][ni], 0, 0, 0);
        }
        __syncthreads();
    }
#pragma unroll
    for (int mi = 0; mi < 4; ++mi)
#pragma unroll
        for (int ni = 0; ni < 4; ++ni) {
            int col = tn * 128 + wn + ni * 16 + l15;
            float bb = bias ? bias[col] : 0.f;
#pragma unroll
            for (int r = 0; r < 4; ++r) {
                int row = tm * 128 + wm + mi * 16 + quad * 4 + r;
                float val = acc[mi][ni][r] * scale + bb;
                if (Cf) Cf[(size_t)row * N + col] = val;
                else    Cb[(size_t)row * N + col] = f2b(val);
            }
        }
}

// ---------------------------------------------------------------------------
// instance decode: 224 instances = 128 (br0) + 64 (br1) + 32 (br2)
// ---------------------------------------------------------------------------
__device__ __forceinline__ void decode_inst(int inst, int& b, int& s, int& h,
                                            int& sl, int& dr, int& phase)
{
    if (inst < 128)      { int j = inst;       b = j >> 6; s = (j >> 3) & 7; h = j & 7; sl = 1024; dr = 1; phase = 0;      }
    else if (inst < 192) { int j = inst - 128; b = j >> 5; s = (j >> 3) & 3; h = j & 7; sl = 2048; dr = 2; phase = h >> 2; }
    else                 { int j = inst - 192; b = j >> 4; s = (j >> 3) & 1; h = j & 7; sl = 4096; dr = 4; phase = h >> 1; }
}

// ---------------------------------------------------------------------------
// Gather K and V^T into per-instance contiguous buffers (internal bf16).
// KG[inst][n][d], VT[inst][d][n]. grid: (224, 32)
// ---------------------------------------------------------------------------
__global__ __launch_bounds__(256) void gather_kv(
    const u16* __restrict__ kk, const u16* __restrict__ vv,
    u16* __restrict__ KG, u16* __restrict__ VT)
{
    int inst = blockIdx.x;
    int b, s, h, sl, dr, phase;
    decode_inst(inst, b, s, h, sl, dr, phase);
    int n0 = blockIdx.y * 32;
    __shared__ __align__(16) u16 tile[32][72];
    int tid = threadIdx.x;
    int row = tid >> 3, ch = (tid & 7) * 8;
    int n = n0 + row;
    size_t pos = (size_t)s * sl + (size_t)n * dr + phase;
    size_t src = (((size_t)b * 8192 + pos) * 8 + h) * 64 + ch;
    *(uint4*)(KG + ((size_t)inst * 1024 + n) * 64 + ch) = *(const uint4*)(kk + src);
    *(uint4*)&tile[row][ch] = *(const uint4*)(vv + src);
    __syncthreads();
    int d = tid >> 2, nn = (tid & 3) * 8;
    __align__(16) u16 tmp[8];
#pragma unroll
    for (int j = 0; j < 8; ++j) tmp[j] = tile[nn + j][d];
    *(uint4*)(VT + ((size_t)inst * 64 + d) * 1024 + n0 + nn) = *(uint4*)tmp;
}

// ---------------------------------------------------------------------------
// Flash attention, S^T formulation; scores arrive in LOG2 domain (log2e folded
// into Q-proj scale), so softmax uses native exp2. LSE kept in log2 units.
// grid: (16 q-tiles, 224 inst); 256 thr = 4 waves x 16 q-rows; K-tile 128.
// ---------------------------------------------------------------------------
__global__ __launch_bounds__(256, 4) void attn_kernel(
    const u16* __restrict__ q, const u16* __restrict__ KG,
    const u16* __restrict__ VT, u16* __restrict__ Og, float* __restrict__ Lg)
{
    const int inst = blockIdx.y, qt = blockIdx.x;
    int b, s, h, sl, dr, phase;
    decode_inst(inst, b, s, h, sl, dr, phase);
    __shared__ __align__(16) u16 k_lds[128][72];
    __shared__ __align__(16) u16 vt_lds[64][136];
    const int tid = threadIdx.x, lane = tid & 63, wv = tid >> 6;
    const int quad = lane >> 4, l15 = lane & 15;

    // Q fragments (B-operand: n = l15 = qrow, k = quad*8+j). q pre-scaled.
    const int qrow = qt * 64 + wv * 16 + l15;
    const size_t qpos = (size_t)s * sl + (size_t)qrow * dr + phase;
    const u16* qbase = q + (((size_t)b * 8192 + qpos) * 8 + h) * 64;
    const short8 qf0 = *(const short8*)(qbase + quad * 8);
    const short8 qf1 = *(const short8*)(qbase + 32 + quad * 8);

    floatx4 oacc[4];
#pragma unroll
    for (int dt = 0; dt < 4; ++dt) oacc[dt] = (floatx4)0.f;
    float mst = -1e30f, lst = 0.f;

    const int srcA = (quad & 1) * 32 + l15;   // source lane for B-frag w=0,1
    const int srcB = srcA + 16;               // source lane for B-frag w=2,3
    const bool hisel = (quad >> 1) != 0;      // tile select (nt parity)

    for (int it = 0; it < 8; ++it) {
        const int k0 = it * 128;
#pragma unroll
        for (int r = 0; r < 4; ++r) {
            int idx = r * 256 + tid;
            int row = idx >> 3, ch = (idx & 7) * 8;
            *(uint4*)&k_lds[row][ch] =
                *(const uint4*)(KG + ((size_t)inst * 1024 + k0 + row) * 64 + ch);
        }
#pragma unroll
        for (int r = 0; r < 4; ++r) {
            int idx = r * 256 + tid;
            int d = idx >> 4, ch = (idx & 15) * 8;
            *(uint4*)&vt_lds[d][ch] =
                *(const uint4*)(VT + ((size_t)inst * 64 + d) * 1024 + k0 + ch);
        }
        __syncthreads();

        // S^T tiles: sacc[nt][r] = S[qrow=l15][key = k0 + nt*16 + quad*4 + r]
        floatx4 sacc[8];
#pragma unroll
        for (int nt = 0; nt < 8; ++nt) {
            sacc[nt] = (floatx4)0.f;
            short8 kf0 = *(const short8*)&k_lds[nt * 16 + l15][quad * 8];
            short8 kf1 = *(const short8*)&k_lds[nt * 16 + l15][32 + quad * 8];
            sacc[nt] = __builtin_amdgcn_mfma_f32_16x16x32_bf16(kf0, qf0, sacc[nt], 0, 0, 0);
            sacc[nt] = __builtin_amdgcn_mfma_f32_16x16x32_bf16(kf1, qf1, sacc[nt], 0, 0, 0);
        }

        // online softmax (log2 domain) for q-row l15
        float mx = sacc[0][0];
#pragma unroll
        for (int nt = 0; nt < 8; ++nt)
#pragma unroll
            for (int r = 0; r < 4; ++r) mx = fmaxf(mx, sacc[nt][r]);
        mx = fmaxf(mx, __shfl_xor(mx, 16, 64));
        mx = fmaxf(mx, __shfl_xor(mx, 32, 64));
        float mnew = fmaxf(mst, mx);
        float alpha = exp2f(mst - mnew);
        float rs = 0.f;
#pragma unroll
        for (int nt = 0; nt < 8; ++nt)
#pragma unroll
            for (int r = 0; r < 4; ++r) {
                float p = exp2f(sacc[nt][r] - mnew);
                sacc[nt][r] = p;
                rs += p;
            }
        rs += __shfl_xor(rs, 16, 64);
        rs += __shfl_xor(rs, 32, 64);
        lst = lst * alpha + rs;
        mst = mnew;
#pragma unroll
        for (int dt = 0; dt < 4; ++dt) oacc[dt] *= alpha;

        // PV: O^T[d][qrow] += V^T[d][key] * P^T[key][qrow], 4 chunks of 32 keys
#pragma unroll
        for (int nc = 0; nc < 4; ++nc) {
            u32 pk00 = pack2(sacc[2 * nc][0], sacc[2 * nc][1]);
            u32 pk01 = pack2(sacc[2 * nc][2], sacc[2 * nc][3]);
            u32 pk10 = pack2(sacc[2 * nc + 1][0], sacc[2 * nc + 1][1]);
            u32 pk11 = pack2(sacc[2 * nc + 1][2], sacc[2 * nc + 1][3]);
            u32 w0a = __shfl((int)pk00, srcA, 64), w0b = __shfl((int)pk10, srcA, 64);
            u32 w1a = __shfl((int)pk01, srcA, 64), w1b = __shfl((int)pk11, srcA, 64);
            u32 w2a = __shfl((int)pk00, srcB, 64), w2b = __shfl((int)pk10, srcB, 64);
            u32 w3a = __shfl((int)pk01, srcB, 64), w3b = __shfl((int)pk11, srcB, 64);
            uint4 bw;
            bw.x = hisel ? w0b : w0a;
            bw.y = hisel ? w1b : w1a;
            bw.z = hisel ? w2b : w2a;
            bw.w = hisel ? w3b : w3a;
            short8 pf = __builtin_bit_cast(short8, bw);
#pragma unroll
            for (int dt = 0; dt < 4; ++dt) {
                short8 vf = *(const short8*)&vt_lds[dt * 16 + l15][nc * 32 + quad * 8];
                oacc[dt] = __builtin_amdgcn_mfma_f32_16x16x32_bf16(vf, pf, oacc[dt], 0, 0, 0);
            }
        }
        __syncthreads();
    }

    // epilogue: O^T -> O via k_lds (free now).
    float inv_l = (lst > 0.f) ? (1.f / lst) : 0.f;
#pragma unroll
    for (int dt = 0; dt < 4; ++dt) {
        u32 lo = pack2(oacc[dt][0] * inv_l, oacc[dt][1] * inv_l);
        u32 hi = pack2(oacc[dt][2] * inv_l, oacc[dt][3] * inv_l);
        uint2 v; v.x = lo; v.y = hi;
        *(uint2*)&k_lds[wv * 16 + l15][dt * 16 + quad * 4] = v;
    }
    __syncthreads();
#pragma unroll
    for (int c = 0; c < 2; ++c) {
        uint4 val = *(const uint4*)&k_lds[wv * 16 + l15][quad * 16 + c * 8];
        *(uint4*)(Og + (((size_t)inst * 1024 + qt * 64 + wv * 16 + l15) * 64
                        + quad * 16 + c * 8)) = val;
    }
    if (quad == 0) {
        // LSE in log2 units
        Lg[(size_t)inst * 1024 + qt * 64 + wv * 16 + l15] = mst + __log2f(lst);
    }
}

// ---------------------------------------------------------------------------
// LSE-weighted merge (log2-domain LSE) -> merged (b, L, H*64) bf16
// ---------------------------------------------------------------------------
__global__ __launch_bounds__(256) void merge_kernel(
    const u16* __restrict__ Og, const float* __restrict__ Lg,
    u16* __restrict__ merged)
{
    int bid = blockIdx.x;
    int b = bid >> 13, l = bid & 8191;
    int t = threadIdx.x;
    int h = t >> 5, d0 = (t & 31) * 2;

    int inst0 = b * 64 + ((l >> 10) << 3) + h;
    int row0 = l & 1023;
    int p1 = l & 2047;
    bool c1 = ((p1 & 1) == (h >> 2));
    int inst1 = 128 + b * 32 + ((l >> 11) << 3) + h;
    int row1 = p1 >> 1;
    int p2 = l & 4095;
    bool c2 = ((p2 & 3) == (h >> 1));
    int inst2 = 192 + b * 16 + ((l >> 12) << 3) + h;
    int row2 = p2 >> 2;

    float lse0 = Lg[(size_t)inst0 * 1024 + row0];
    float lse1 = c1 ? Lg[(size_t)inst1 * 1024 + row1] : -1e30f;
    float lse2 = c2 ? Lg[(size_t)inst2 * 1024 + row2] : -1e30f;
    float m = fmaxf(lse0, fmaxf(lse1, lse2));
    float w0 = exp2f(lse0 - m);
    float w1 = c1 ? exp2f(lse1 - m) : 0.f;
    float w2 = c2 ? exp2f(lse2 - m) : 0.f;
    float inv = 1.f / (w0 + w1 + w2);
    w0 *= inv; w1 *= inv; w2 *= inv;

    u32 u0 = *(const u32*)(Og + ((size_t)inst0 * 1024 + row0) * 64 + d0);
    u32 u1 = c1 ? *(const u32*)(Og + ((size_t)inst1 * 1024 + row1) * 64 + d0) : 0u;
    u32 u2 = c2 ? *(const u32*)(Og + ((size_t)inst2 * 1024 + row2) * 64 + d0) : 0u;
    float a0 = b2f((u16)(u0 & 0xffff)), e0 = b2f((u16)(u0 >> 16));
    float a1 = b2f((u16)(u1 & 0xffff)), e1 = b2f((u16)(u1 >> 16));
    float a2 = b2f((u16)(u2 & 0xffff)), e2 = b2f((u16)(u2 >> 16));
    float ra = w0 * a0 + w1 * a1 + w2 * a2;
    float rb = w0 * e0 + w1 * e1 + w2 * e2;
    u32 outp = pack2(ra, rb);
    *(u32*)(merged + (((size_t)b * 8192 + l) * 8 + h) * 64 + d0) = outp;
}

// ---------------------------------------------------------------------------
extern "C" void kernel_launch(void* const* d_in, const int* in_sizes, int n_in,
                              void* d_out, int out_size, void* d_ws, size_t ws_size,
                              hipStream_t stream)
{
    (void)in_sizes; (void)n_in; (void)out_size; (void)ws_size;
    const float* query = (const float*)d_in[0];
    const float* key_  = (const float*)d_in[1];
    const float* value = (const float*)d_in[2];
    const float* Wq    = (const float*)d_in[3];
    const float* Wk    = (const float*)d_in[4];
    const float* Wv    = (const float*)d_in[5];
    const float* Wo    = (const float*)d_in[6];
    const float* bo    = (const float*)d_in[7];

    char* ws = (char*)d_ws;
    const size_t SZ_PROJ = (size_t)16384 * 512 * 2;       // 16 MiB each (bf16)
    const size_t SZ_KG   = (size_t)224 * 1024 * 64 * 2;   // 28 MiB
    const size_t SZ_LG   = (size_t)224 * 1024 * 4;
    u16*   qb     = (u16*)(ws);
    u16*   kb     = (u16*)(ws + SZ_PROJ);
    u16*   vb     = (u16*)(ws + 2 * SZ_PROJ);
    u16*   KG     = (u16*)(ws + 3 * SZ_PROJ);
    u16*   VT     = (u16*)(ws + 3 * SZ_PROJ + SZ_KG);
    u16*   Og     = (u16*)(ws + 3 * SZ_PROJ + 2 * SZ_KG);
    float* Lg     = (float*)(ws + 3 * SZ_PROJ + 3 * SZ_KG);
    u16*   merged = (u16*)(ws + 3 * SZ_PROJ + 3 * SZ_KG + SZ_LG);

    const int M = 16384, N = 512, K = 512;
    // 64^-0.5 * log2(e): scores come out of QK^T in log2 units
    const float SCALE = 0.125f * 1.44269504088896f;

    gemm_bt_bias<true><<<dim3(128, 4), 256, 0, stream>>>(query, Wq, qb, nullptr, nullptr, M, N, K, SCALE);
    gemm_bt_bias<true><<<dim3(128, 4), 256, 0, stream>>>(key_,  Wk, kb, nullptr, nullptr, M, N, K, 1.0f);
    gemm_bt_bias<true><<<dim3(128, 4), 256, 0, stream>>>(value, Wv, vb, nullptr, nullptr, M, N, K, 1.0f);
    gather_kv<<<dim3(224, 32), 256, 0, stream>>>(kb, vb, KG, VT);
    attn_kernel<<<dim3(16, 224), 256, 0, stream>>>(qb, KG, VT, Og, Lg);
    merge_kernel<<<16384, 256, 0, stream>>>(Og, Lg, merged);
    gemm_bt_bias<false><<<dim3(128, 4), 256, 0, stream>>>(merged, Wo, nullptr, (float*)d_out, bo, M, N, K, 1.0f);
}

// Round 7
// 408.972 us; speedup vs baseline: 1.1536x; 1.1536x over previous
//
#include <hip/hip_runtime.h>
#include <hip/hip_bf16.h>

typedef unsigned short u16;
typedef unsigned int u32;
typedef __attribute__((ext_vector_type(8))) short short8;
typedef __attribute__((ext_vector_type(4))) float floatx4;

__device__ __forceinline__ float b2f(u16 u) {
    u32 x = ((u32)u) << 16;
    return __builtin_bit_cast(float, x);
}
// scalar f32 -> bf16 (RNE), branch-free
__device__ __forceinline__ u16 f2b(float f) {
    u32 x = __builtin_bit_cast(u32, f);
    return (u16)((x + 0x7fffu + ((x >> 16) & 1u)) >> 16);
}
// packed f32x2 -> bf16x2: lowers to single v_cvt_pk_bf16_f32 (verified r4:
// this path gave the fast GEMM staging; r6's manual fallback cost +50us)
__device__ __forceinline__ u32 pack2(float lo, float hi) {
    float2 f; f.x = lo; f.y = hi;
    __hip_bfloat162 h = __float22bfloat162_rn(f);
    u32 r;
    __builtin_memcpy(&r, &h, 4);
    return r;
}
// native 2^x (v_exp_f32 computes exp2 directly)
__device__ __forceinline__ float fexp2(float x) {
#if __has_builtin(__builtin_amdgcn_exp2f)
    return __builtin_amdgcn_exp2f(x);
#else
    return __expf(x * 0.6931471805599453f);
#endif
}

// ---------------------------------------------------------------------------
// GEMM: C[m,n] = scale * sum_k A[m,k] * B[n,k]  (+ bias[n])
// A: (M,K) row-major, f32 (AF32=true) or bf16 (false)
// B: (N,K) row-major f32 (weights straight from d_in)
// C: bf16 (Cb) or f32 (Cf). f32 acc via MFMA. 128x128 tile, BK=64.
// ---------------------------------------------------------------------------
template<bool AF32>
__global__ __launch_bounds__(256) void gemm_bt_bias(
    const void* __restrict__ Ap, const float* __restrict__ B,
    u16* __restrict__ Cb, float* __restrict__ Cf, const float* __restrict__ bias,
    int M, int N, int K, float scale)
{
    __shared__ __align__(16) u16 a_lds[128][72];
    __shared__ __align__(16) u16 b_lds[128][72];
    const int tid = threadIdx.x;
    const int lane = tid & 63, wv = tid >> 6;
    const int quad = lane >> 4, l15 = lane & 15;
    const int tm = blockIdx.x, tn = blockIdx.y;
    const int wm = (wv >> 1) * 64, wn = (wv & 1) * 64;
    (void)M;

    floatx4 acc[4][4];
#pragma unroll
    for (int i = 0; i < 4; ++i)
#pragma unroll
        for (int j = 0; j < 4; ++j) acc[i][j] = (floatx4)0.f;

    for (int k0 = 0; k0 < K; k0 += 64) {
#pragma unroll
        for (int r = 0; r < 4; ++r) {
            int idx = r * 256 + tid;
            int row = idx >> 3, ch = (idx & 7) * 8;
            if constexpr (AF32) {
                const float* A = (const float*)Ap;
                const float* src = A + (size_t)(tm * 128 + row) * K + k0 + ch;
                float4 f0 = *(const float4*)src;
                float4 f1 = *(const float4*)(src + 4);
                uint4 pk;
                pk.x = pack2(f0.x, f0.y);
                pk.y = pack2(f0.z, f0.w);
                pk.z = pack2(f1.x, f1.y);
                pk.w = pack2(f1.z, f1.w);
                *(uint4*)&a_lds[row][ch] = pk;
            } else {
                const u16* A = (const u16*)Ap;
                *(uint4*)&a_lds[row][ch] =
                    *(const uint4*)(A + (size_t)(tm * 128 + row) * K + k0 + ch);
            }
            {
                const float* src = B + (size_t)(tn * 128 + row) * K + k0 + ch;
                float4 f0 = *(const float4*)src;
                float4 f1 = *(const float4*)(src + 4);
                uint4 pk;
                pk.x = pack2(f0.x, f0.y);
                pk.y = pack2(f0.z, f0.w);
                pk.z = pack2(f1.x, f1.y);
                pk.w = pack2(f1.z, f1.w);
                *(uint4*)&b_lds[row][ch] = pk;
            }
        }
        __syncthreads();
#pragma unroll
        for (int dc = 0; dc < 2; ++dc) {
            short8 af[4], bf[4];
#pragma unroll
            for (int mi = 0; mi < 4; ++mi)
                af[mi] = *(const short8*)&a_lds[wm + mi * 16 + l15][dc * 32 + quad * 8];
#pragma unroll
            for (int ni = 0; ni < 4; ++ni)
                bf[ni] = *(const short8*)&b_lds[wn + ni * 16 + l15][dc * 32 + quad * 8];
#pragma unroll
            for (int mi = 0; mi < 4; ++mi)
#pragma unroll
                for (int ni = 0; ni < 4; ++ni)
                    acc[mi][ni] = __builtin_amdgcn_mfma_f32_16x16x32_bf16(
                        af[mi], bf[ni], acc[mi][ni], 0, 0, 0);
        }
        __syncthreads();
    }
#pragma unroll
    for (int mi = 0; mi < 4; ++mi)
#pragma unroll
        for (int ni = 0; ni < 4; ++ni) {
            int col = tn * 128 + wn + ni * 16 + l15;
            float bb = bias ? bias[col] : 0.f;
#pragma unroll
            for (int r = 0; r < 4; ++r) {
                int row = tm * 128 + wm + mi * 16 + quad * 4 + r;
                float val = acc[mi][ni][r] * scale + bb;
                if (Cf) Cf[(size_t)row * N + col] = val;
                else    Cb[(size_t)row * N + col] = f2b(val);
            }
        }
}

// ---------------------------------------------------------------------------
// instance decode: 224 instances = 128 (br0) + 64 (br1) + 32 (br2)
// ---------------------------------------------------------------------------
__device__ __forceinline__ void decode_inst(int inst, int& b, int& s, int& h,
                                            int& sl, int& dr, int& phase)
{
    if (inst < 128)      { int j = inst;       b = j >> 6; s = (j >> 3) & 7; h = j & 7; sl = 1024; dr = 1; phase = 0;      }
    else if (inst < 192) { int j = inst - 128; b = j >> 5; s = (j >> 3) & 3; h = j & 7; sl = 2048; dr = 2; phase = h >> 2; }
    else                 { int j = inst - 192; b = j >> 4; s = (j >> 3) & 1; h = j & 7; sl = 4096; dr = 4; phase = h >> 1; }
}

// ---------------------------------------------------------------------------
// Gather K and V^T into per-instance contiguous buffers (internal bf16).
// KG[inst][n][d], VT[inst][d][n]. grid: (224, 32)
// ---------------------------------------------------------------------------
__global__ __launch_bounds__(256) void gather_kv(
    const u16* __restrict__ kk, const u16* __restrict__ vv,
    u16* __restrict__ KG, u16* __restrict__ VT)
{
    int inst = blockIdx.x;
    int b, s, h, sl, dr, phase;
    decode_inst(inst, b, s, h, sl, dr, phase);
    int n0 = blockIdx.y * 32;
    __shared__ __align__(16) u16 tile[32][72];
    int tid = threadIdx.x;
    int row = tid >> 3, ch = (tid & 7) * 8;
    int n = n0 + row;
    size_t pos = (size_t)s * sl + (size_t)n * dr + phase;
    size_t src = (((size_t)b * 8192 + pos) * 8 + h) * 64 + ch;
    *(uint4*)(KG + ((size_t)inst * 1024 + n) * 64 + ch) = *(const uint4*)(kk + src);
    *(uint4*)&tile[row][ch] = *(const uint4*)(vv + src);
    __syncthreads();
    int d = tid >> 2, nn = (tid & 3) * 8;
    __align__(16) u16 tmp[8];
#pragma unroll
    for (int j = 0; j < 8; ++j) tmp[j] = tile[nn + j][d];
    *(uint4*)(VT + ((size_t)inst * 64 + d) * 1024 + n0 + nn) = *(uint4*)tmp;
}

// ---------------------------------------------------------------------------
// Flash attention, S^T formulation; scores arrive in LOG2 domain (log2e folded
// into Q-proj scale); softmax via native v_exp_f32. LSE kept in log2 units.
// grid: (16 q-tiles, 224 inst); 256 thr = 4 waves x 16 q-rows; K-tile 128.
// ---------------------------------------------------------------------------
__global__ __launch_bounds__(256, 4) void attn_kernel(
    const u16* __restrict__ q, const u16* __restrict__ KG,
    const u16* __restrict__ VT, u16* __restrict__ Og, float* __restrict__ Lg)
{
    const int inst = blockIdx.y, qt = blockIdx.x;
    int b, s, h, sl, dr, phase;
    decode_inst(inst, b, s, h, sl, dr, phase);
    __shared__ __align__(16) u16 k_lds[128][72];
    __shared__ __align__(16) u16 vt_lds[64][136];
    const int tid = threadIdx.x, lane = tid & 63, wv = tid >> 6;
    const int quad = lane >> 4, l15 = lane & 15;

    // Q fragments (B-operand: n = l15 = qrow, k = quad*8+j). q pre-scaled.
    const int qrow = qt * 64 + wv * 16 + l15;
    const size_t qpos = (size_t)s * sl + (size_t)qrow * dr + phase;
    const u16* qbase = q + (((size_t)b * 8192 + qpos) * 8 + h) * 64;
    const short8 qf0 = *(const short8*)(qbase + quad * 8);
    const short8 qf1 = *(const short8*)(qbase + 32 + quad * 8);

    floatx4 oacc[4];
#pragma unroll
    for (int dt = 0; dt < 4; ++dt) oacc[dt] = (floatx4)0.f;
    float mst = -1e30f, lst = 0.f;

    const int srcA = (quad & 1) * 32 + l15;   // source lane for B-frag w=0,1
    const int srcB = srcA + 16;               // source lane for B-frag w=2,3
    const bool hisel = (quad >> 1) != 0;      // tile select (nt parity)

    for (int it = 0; it < 8; ++it) {
        const int k0 = it * 128;
#pragma unroll
        for (int r = 0; r < 4; ++r) {
            int idx = r * 256 + tid;
            int row = idx >> 3, ch = (idx & 7) * 8;
            *(uint4*)&k_lds[row][ch] =
                *(const uint4*)(KG + ((size_t)inst * 1024 + k0 + row) * 64 + ch);
        }
#pragma unroll
        for (int r = 0; r < 4; ++r) {
            int idx = r * 256 + tid;
            int d = idx >> 4, ch = (idx & 15) * 8;
            *(uint4*)&vt_lds[d][ch] =
                *(const uint4*)(VT + ((size_t)inst * 64 + d) * 1024 + k0 + ch);
        }
        __syncthreads();

        // S^T tiles: sacc[nt][r] = S[qrow=l15][key = k0 + nt*16 + quad*4 + r]
        floatx4 sacc[8];
#pragma unroll
        for (int nt = 0; nt < 8; ++nt) {
            sacc[nt] = (floatx4)0.f;
            short8 kf0 = *(const short8*)&k_lds[nt * 16 + l15][quad * 8];
            short8 kf1 = *(const short8*)&k_lds[nt * 16 + l15][32 + quad * 8];
            sacc[nt] = __builtin_amdgcn_mfma_f32_16x16x32_bf16(kf0, qf0, sacc[nt], 0, 0, 0);
            sacc[nt] = __builtin_amdgcn_mfma_f32_16x16x32_bf16(kf1, qf1, sacc[nt], 0, 0, 0);
        }

        // online softmax (log2 domain) for q-row l15
        float mx = sacc[0][0];
#pragma unroll
        for (int nt = 0; nt < 8; ++nt)
#pragma unroll
            for (int r = 0; r < 4; ++r) mx = fmaxf(mx, sacc[nt][r]);
        mx = fmaxf(mx, __shfl_xor(mx, 16, 64));
        mx = fmaxf(mx, __shfl_xor(mx, 32, 64));
        float mnew = fmaxf(mst, mx);
        float alpha = fexp2(mst - mnew);
        float rs = 0.f;
#pragma unroll
        for (int nt = 0; nt < 8; ++nt)
#pragma unroll
            for (int r = 0; r < 4; ++r) {
                float p = fexp2(sacc[nt][r] - mnew);
                sacc[nt][r] = p;
                rs += p;
            }
        rs += __shfl_xor(rs, 16, 64);
        rs += __shfl_xor(rs, 32, 64);
        lst = lst * alpha + rs;
        mst = mnew;
#pragma unroll
        for (int dt = 0; dt < 4; ++dt) oacc[dt] *= alpha;

        // PV: O^T[d][qrow] += V^T[d][key] * P^T[key][qrow], 4 chunks of 32 keys
#pragma unroll
        for (int nc = 0; nc < 4; ++nc) {
            u32 pk00 = pack2(sacc[2 * nc][0], sacc[2 * nc][1]);
            u32 pk01 = pack2(sacc[2 * nc][2], sacc[2 * nc][3]);
            u32 pk10 = pack2(sacc[2 * nc + 1][0], sacc[2 * nc + 1][1]);
            u32 pk11 = pack2(sacc[2 * nc + 1][2], sacc[2 * nc + 1][3]);
            u32 w0a = __shfl((int)pk00, srcA, 64), w0b = __shfl((int)pk10, srcA, 64);
            u32 w1a = __shfl((int)pk01, srcA, 64), w1b = __shfl((int)pk11, srcA, 64);
            u32 w2a = __shfl((int)pk00, srcB, 64), w2b = __shfl((int)pk10, srcB, 64);
            u32 w3a = __shfl((int)pk01, srcB, 64), w3b = __shfl((int)pk11, srcB, 64);
            uint4 bw;
            bw.x = hisel ? w0b : w0a;
            bw.y = hisel ? w1b : w1a;
            bw.z = hisel ? w2b : w2a;
            bw.w = hisel ? w3b : w3a;
            short8 pf = __builtin_bit_cast(short8, bw);
#pragma unroll
            for (int dt = 0; dt < 4; ++dt) {
                short8 vf = *(const short8*)&vt_lds[dt * 16 + l15][nc * 32 + quad * 8];
                oacc[dt] = __builtin_amdgcn_mfma_f32_16x16x32_bf16(vf, pf, oacc[dt], 0, 0, 0);
            }
        }
        __syncthreads();
    }

    // epilogue: O^T -> O via k_lds (free now).
    float inv_l = (lst > 0.f) ? (1.f / lst) : 0.f;
#pragma unroll
    for (int dt = 0; dt < 4; ++dt) {
        u32 lo = pack2(oacc[dt][0] * inv_l, oacc[dt][1] * inv_l);
        u32 hi = pack2(oacc[dt][2] * inv_l, oacc[dt][3] * inv_l);
        uint2 v; v.x = lo; v.y = hi;
        *(uint2*)&k_lds[wv * 16 + l15][dt * 16 + quad * 4] = v;
    }
    __syncthreads();
#pragma unroll
    for (int c = 0; c < 2; ++c) {
        uint4 val = *(const uint4*)&k_lds[wv * 16 + l15][quad * 16 + c * 8];
        *(uint4*)(Og + (((size_t)inst * 1024 + qt * 64 + wv * 16 + l15) * 64
                        + quad * 16 + c * 8)) = val;
    }
    if (quad == 0) {
        // LSE in log2 units
        Lg[(size_t)inst * 1024 + qt * 64 + wv * 16 + l15] = mst + __log2f(lst);
    }
}

// ---------------------------------------------------------------------------
// LSE-weighted merge (log2-domain LSE) -> merged (b, L, H*64) bf16
// ---------------------------------------------------------------------------
__global__ __launch_bounds__(256) void merge_kernel(
    const u16* __restrict__ Og, const float* __restrict__ Lg,
    u16* __restrict__ merged)
{
    int bid = blockIdx.x;
    int b = bid >> 13, l = bid & 8191;
    int t = threadIdx.x;
    int h = t >> 5, d0 = (t & 31) * 2;

    int inst0 = b * 64 + ((l >> 10) << 3) + h;
    int row0 = l & 1023;
    int p1 = l & 2047;
    bool c1 = ((p1 & 1) == (h >> 2));
    int inst1 = 128 + b * 32 + ((l >> 11) << 3) + h;
    int row1 = p1 >> 1;
    int p2 = l & 4095;
    bool c2 = ((p2 & 3) == (h >> 1));
    int inst2 = 192 + b * 16 + ((l >> 12) << 3) + h;
    int row2 = p2 >> 2;

    float lse0 = Lg[(size_t)inst0 * 1024 + row0];
    float lse1 = c1 ? Lg[(size_t)inst1 * 1024 + row1] : -1e30f;
    float lse2 = c2 ? Lg[(size_t)inst2 * 1024 + row2] : -1e30f;
    float m = fmaxf(lse0, fmaxf(lse1, lse2));
    float w0 = fexp2(lse0 - m);
    float w1 = c1 ? fexp2(lse1 - m) : 0.f;
    float w2 = c2 ? fexp2(lse2 - m) : 0.f;
    float inv = 1.f / (w0 + w1 + w2);
    w0 *= inv; w1 *= inv; w2 *= inv;

    u32 u0 = *(const u32*)(Og + ((size_t)inst0 * 1024 + row0) * 64 + d0);
    u32 u1 = c1 ? *(const u32*)(Og + ((size_t)inst1 * 1024 + row1) * 64 + d0) : 0u;
    u32 u2 = c2 ? *(const u32*)(Og + ((size_t)inst2 * 1024 + row2) * 64 + d0) : 0u;
    float a0 = b2f((u16)(u0 & 0xffff)), e0 = b2f((u16)(u0 >> 16));
    float a1 = b2f((u16)(u1 & 0xffff)), e1 = b2f((u16)(u1 >> 16));
    float a2 = b2f((u16)(u2 & 0xffff)), e2 = b2f((u16)(u2 >> 16));
    float ra = w0 * a0 + w1 * a1 + w2 * a2;
    float rb = w0 * e0 + w1 * e1 + w2 * e2;
    u32 outp = pack2(ra, rb);
    *(u32*)(merged + (((size_t)b * 8192 + l) * 8 + h) * 64 + d0) = outp;
}

// ---------------------------------------------------------------------------
extern "C" void kernel_launch(void* const* d_in, const int* in_sizes, int n_in,
                              void* d_out, int out_size, void* d_ws, size_t ws_size,
                              hipStream_t stream)
{
    (void)in_sizes; (void)n_in; (void)out_size; (void)ws_size;
    const float* query = (const float*)d_in[0];
    const float* key_  = (const float*)d_in[1];
    const float* value = (const float*)d_in[2];
    const float* Wq    = (const float*)d_in[3];
    const float* Wk    = (const float*)d_in[4];
    const float* Wv    = (const float*)d_in[5];
    const float* Wo    = (const float*)d_in[6];
    const float* bo    = (const float*)d_in[7];

    char* ws = (char*)d_ws;
    const size_t SZ_PROJ = (size_t)16384 * 512 * 2;       // 16 MiB each (bf16)
    const size_t SZ_KG   = (size_t)224 * 1024 * 64 * 2;   // 28 MiB
    const size_t SZ_LG   = (size_t)224 * 1024 * 4;
    u16*   qb     = (u16*)(ws);
    u16*   kb     = (u16*)(ws + SZ_PROJ);
    u16*   vb     = (u16*)(ws + 2 * SZ_PROJ);
    u16*   KG     = (u16*)(ws + 3 * SZ_PROJ);
    u16*   VT     = (u16*)(ws + 3 * SZ_PROJ + SZ_KG);
    u16*   Og     = (u16*)(ws + 3 * SZ_PROJ + 2 * SZ_KG);
    float* Lg     = (float*)(ws + 3 * SZ_PROJ + 3 * SZ_KG);
    u16*   merged = (u16*)(ws + 3 * SZ_PROJ + 3 * SZ_KG + SZ_LG);

    const int M = 16384, N = 512, K = 512;
    // 64^-0.5 * log2(e): scores come out of QK^T in log2 units
    const float SCALE = 0.125f * 1.44269504088896f;

    gemm_bt_bias<true><<<dim3(128, 4), 256, 0, stream>>>(query, Wq, qb, nullptr, nullptr, M, N, K, SCALE);
    gemm_bt_bias<true><<<dim3(128, 4), 256, 0, stream>>>(key_,  Wk, kb, nullptr, nullptr, M, N, K, 1.0f);
    gemm_bt_bias<true><<<dim3(128, 4), 256, 0, stream>>>(value, Wv, vb, nullptr, nullptr, M, N, K, 1.0f);
    gather_kv<<<dim3(224, 32), 256, 0, stream>>>(kb, vb, KG, VT);
    attn_kernel<<<dim3(16, 224), 256, 0, stream>>>(qb, KG, VT, Og, Lg);
    merge_kernel<<<16384, 256, 0, stream>>>(Og, Lg, merged);
    gemm_bt_bias<false><<<dim3(128, 4), 256, 0, stream>>>(merged, Wo, nullptr, (float*)d_out, bo, M, N, K, 1.0f);
}